// Round 1
// baseline (5783.794 us; speedup 1.0000x reference)
//
#include <hip/hip_runtime.h>
#include <hip/hip_bf16.h>

// alphaLSTMNetwork: B=2048 sequential steps, E=16 elevators.
// Decomposition:
//   G1: pg0  = feat @ pre_Wih0^T + bih0 + bhh0            [B*16, 256]  (parallel)
//   G2: pgo  = feat @ out_Wih[:,64:]^T + bih + bhh        [B*16, 512]  (parallel)
//   K2: per-elevator 2-layer pre-LSTM + fc recurrence     (16 blocks, seq over t)
//   G4: gih  = x @ comm_Wih0^T + bih0 + bhh0              [B*16, 128]  (parallel)
//   K3: comm alpha-LSTM, 48 micro-steps, state resets/t   (1 wave per t, parallel)
//   G6: gg   = group @ out_Wih[:,:64]^T                   [B, 512]     (parallel)
//   K4: per-elevator out-LSTM recurrence                  (16 blocks, seq over t)
//   K5: heads (tar/dir softmax)                           (parallel)
// Workspace: B*17984 floats = ~140.5 MB.

#define E_ 16
#define F_ 128

__device__ __forceinline__ float sigf(float x) { return 1.0f / (1.0f + __expf(-x)); }
__device__ __forceinline__ float tanhf_(float x) {
  float e = __expf(2.0f * x);
  return 1.0f - 2.0f / (e + 1.0f);
}
__device__ __forceinline__ float lane_bcast(float v, int k) {
  return __int_as_float(__builtin_amdgcn_readlane(__float_as_int(v), k));
}

// ---------------------------------------------------------------------------
// Generic skinny GEMM: C[m,n] = sum_k A[m,k]*W[n, co+k] (+b1[n]+b2[n])
// Tile 64m x 128n, KC=64, block 256, 4x8 microtile. K in {64,128}, N % 128 == 0... 
// (N=256/512/128 handled via grid.y; M % 64 == 0)
// ---------------------------------------------------------------------------
__global__ __launch_bounds__(256) void gemm_k(
    const float* __restrict__ A, int lda,
    const float* __restrict__ W, int ldw, int co,
    const float* __restrict__ b1, const float* __restrict__ b2,
    float* __restrict__ C, int N, int K) {
  __shared__ float As[64 * 65];
  __shared__ float Ws[128 * 65];
  const int tid = threadIdx.x;
  const int m0 = blockIdx.x * 64;
  const int n0 = blockIdx.y * 128;
  const int rr = tid >> 4;          // 0..15
  const int c4 = (tid & 15) << 2;   // 0,4,...,60
  const int tm = tid >> 4;          // row group 0..15 (4 rows each)
  const int tn = tid & 15;          // col group 0..15 (8 cols each)

  float acc[4][8];
#pragma unroll
  for (int i = 0; i < 4; ++i)
#pragma unroll
    for (int j = 0; j < 8; ++j) acc[i][j] = 0.0f;

  for (int kk = 0; kk < K; kk += 64) {
#pragma unroll
    for (int p = 0; p < 4; ++p) {
      const int r = rr + p * 16;
      const float4 v = *(const float4*)(A + (size_t)(m0 + r) * lda + kk + c4);
      float* dst = &As[r * 65 + c4];
      dst[0] = v.x; dst[1] = v.y; dst[2] = v.z; dst[3] = v.w;
    }
#pragma unroll
    for (int p = 0; p < 8; ++p) {
      const int n = rr + p * 16;
      const float4 v = *(const float4*)(W + (size_t)(n0 + n) * ldw + co + kk + c4);
      float* dst = &Ws[n * 65 + c4];
      dst[0] = v.x; dst[1] = v.y; dst[2] = v.z; dst[3] = v.w;
    }
    __syncthreads();
#pragma unroll 4
    for (int k = 0; k < 64; ++k) {
      float a[4], wv[8];
#pragma unroll
      for (int i = 0; i < 4; ++i) a[i] = As[(tm * 4 + i) * 65 + k];
#pragma unroll
      for (int j = 0; j < 8; ++j) wv[j] = Ws[(tn * 8 + j) * 65 + k];
#pragma unroll
      for (int i = 0; i < 4; ++i)
#pragma unroll
        for (int j = 0; j < 8; ++j) acc[i][j] += a[i] * wv[j];
    }
    __syncthreads();
  }
#pragma unroll
  for (int i = 0; i < 4; ++i) {
    const int m = m0 + tm * 4 + i;
#pragma unroll
    for (int j = 0; j < 8; ++j) {
      const int n = n0 + tn * 8 + j;
      float v = acc[i][j];
      if (b1) v += b1[n];
      if (b2) v += b2[n];
      C[(size_t)m * N + n] = v;
    }
  }
}

// ---------------------------------------------------------------------------
// K2: per-elevator pre-LSTM (2 layers) + fc. One block per elevator, 512 thr.
// thread t: gate g = t>>1, half = t&1 (k-split of the dot). fc: fj=t>>3, oct=t&7.
// ---------------------------------------------------------------------------
__global__ __launch_bounds__(512) void k2_pre(
    const float* __restrict__ pg0, const float* __restrict__ preh,
    const float* __restrict__ prec, const float* __restrict__ Whh0,
    const float* __restrict__ Wih1, const float* __restrict__ Whh1,
    const float* __restrict__ bih1, const float* __restrict__ bhh1,
    const float* __restrict__ fcW, const float* __restrict__ fcb,
    float* __restrict__ xout, int B) {
  const int e = blockIdx.x;
  const int t = threadIdx.x;
  const int g = t >> 1, half = t & 1;
  const int fj = t >> 3, oct = t & 7;
  __shared__ float h0s[64], h1s[64], c0s[64], c1s[64], gb0[256], gb1[256];

  float w0[32];
#pragma unroll
  for (int i = 0; i < 32; ++i) w0[i] = Whh0[g * 64 + half * 32 + i];
  float w1[64];
  {
    const float* src = half ? Whh1 : Wih1;
#pragma unroll
    for (int i = 0; i < 64; ++i) w1[i] = src[g * 64 + i];
  }
  float wf[8];
#pragma unroll
  for (int i = 0; i < 8; ++i) wf[i] = fcW[fj * 64 + oct * 8 + i];
  const float b1v = bih1[g] + bhh1[g];
  const float fbv = fcb[fj];

  if (t < 64) {
    h0s[t] = preh[e * 128 + t];      h1s[t] = preh[e * 128 + 64 + t];
    c0s[t] = prec[e * 128 + t];      c1s[t] = prec[e * 128 + 64 + t];
  }
  __syncthreads();

  float pgv = (half == 0) ? pg0[(size_t)e * 256 + g] : 0.0f;  // t=0 prefetch
  for (int tt = 0; tt < B; ++tt) {
    // ---- layer0: gates = pg0 + h0 @ Whh0^T
    float acc = 0.0f;
#pragma unroll
    for (int i = 0; i < 32; i += 4) {
      const float4 hv = *(const float4*)&h0s[half * 32 + i];
      acc += w0[i] * hv.x + w0[i + 1] * hv.y + w0[i + 2] * hv.z + w0[i + 3] * hv.w;
    }
    acc += __shfl_xor(acc, 1);
    if (half == 0) {
      const float pre = acc + pgv;
      gb0[g] = ((g >> 6) == 2) ? tanhf_(pre) : sigf(pre);
    }
    __syncthreads();
    if (t < 64) {
      const float iv = gb0[t], fv = gb0[64 + t], gv = gb0[128 + t], ov = gb0[192 + t];
      const float c = fv * c0s[t] + iv * gv;
      c0s[t] = c;
      h0s[t] = ov * tanhf_(c);
    }
    __syncthreads();
    // ---- layer1: gates = h0 @ Wih1^T + h1 @ Whh1^T + b
    const float* hsrc = half ? h1s : h0s;
    float acc2 = 0.0f;
#pragma unroll
    for (int i = 0; i < 64; i += 4) {
      const float4 hv = *(const float4*)&hsrc[i];
      acc2 += w1[i] * hv.x + w1[i + 1] * hv.y + w1[i + 2] * hv.z + w1[i + 3] * hv.w;
    }
    acc2 += __shfl_xor(acc2, 1);
    float pgnext = 0.0f;
    if (half == 0 && tt + 1 < B) pgnext = pg0[((size_t)(tt + 1) * E_ + e) * 256 + g];
    if (half == 0) {
      const float pre = acc2 + b1v;
      gb1[g] = ((g >> 6) == 2) ? tanhf_(pre) : sigf(pre);
    }
    __syncthreads();
    if (t < 64) {
      const float iv = gb1[t], fv = gb1[64 + t], gv = gb1[128 + t], ov = gb1[192 + t];
      const float c = fv * c1s[t] + iv * gv;
      c1s[t] = c;
      h1s[t] = ov * tanhf_(c);
    }
    __syncthreads();
    // ---- fc + leaky_relu(0.05)
    float a3 = 0.0f;
#pragma unroll
    for (int i = 0; i < 8; ++i) a3 += wf[i] * h1s[oct * 8 + i];
    a3 += __shfl_xor(a3, 1);
    a3 += __shfl_xor(a3, 2);
    a3 += __shfl_xor(a3, 4);
    if (oct == 0) {
      const float xv = a3 + fbv;
      xout[(size_t)tt * (E_ * 64) + e * 64 + fj] = (xv > 0.0f) ? xv : 0.05f * xv;
    }
    pgv = pgnext;
  }
}

// ---------------------------------------------------------------------------
// K3: communication alpha-LSTM. One wave per timestep t (state resets each t).
// lane l holds gates l and l+64 (CH=32: i=0..31,f=32..63 | g=64..95,o=96..127).
// Weights in registers, h broadcast via readlane, i/f/g/o swap via shfl_xor(32).
// ---------------------------------------------------------------------------
__global__ __launch_bounds__(256) void k3_comm(
    const float* __restrict__ gih0, const float* __restrict__ Whh0,
    const float* __restrict__ Wih1, const float* __restrict__ Whh1,
    const float* __restrict__ bih1, const float* __restrict__ bhh1,
    float* __restrict__ grp, int B) {
  const int w = threadIdx.x >> 6;
  const int l = threadIdx.x & 63;
  const int t = blockIdx.x * 4 + w;

  float wh0a[32], wh0b[32], wi1a[32], wi1b[32], wh1a[32], wh1b[32];
#pragma unroll
  for (int i = 0; i < 32; ++i) {
    wh0a[i] = Whh0[l * 32 + i];         wh0b[i] = Whh0[(l + 64) * 32 + i];
    wi1a[i] = Wih1[l * 32 + i];         wi1b[i] = Wih1[(l + 64) * 32 + i];
    wh1a[i] = Whh1[l * 32 + i];         wh1b[i] = Whh1[(l + 64) * 32 + i];
  }
  const float cb1a = bih1[l] + bhh1[l];
  const float cb1b = bih1[l + 64] + bhh1[l + 64];

  float h0 = 0.0f, c0 = 0.0f, h1 = 0.0f, c1 = 0.0f;
  float al = 1.0f;
  const float* gbase = gih0 + (size_t)t * (E_ * 128);
  for (int r = 0; r < 3; ++r) {
    for (int e = 0; e < E_; ++e) {
      // layer0: gih already holds x-part + biases; add h0 @ Whh0^T
      float ga = gbase[e * 128 + l];
      float gb = gbase[e * 128 + l + 64];
#pragma unroll
      for (int k = 0; k < 32; ++k) {
        const float hv = lane_bcast(h0, k);
        ga += wh0a[k] * hv;
        gb += wh0b[k] * hv;
      }
      {
        const float fa = __shfl_xor(ga, 32);  // lane j<32: f_j
        const float ob = __shfl_xor(gb, 32);  // lane j<32: o_j
        c0 = sigf(fa) * c0 + al * sigf(ga) * tanhf_(gb);
        h0 = sigf(ob) * tanhf_(c0);
      }
      // layer1
      float ga1 = cb1a, gb1 = cb1b;
#pragma unroll
      for (int k = 0; k < 32; ++k) {
        const float hv = lane_bcast(h0, k);
        ga1 += wi1a[k] * hv;
        gb1 += wi1b[k] * hv;
      }
#pragma unroll
      for (int k = 0; k < 32; ++k) {
        const float hv = lane_bcast(h1, k);
        ga1 += wh1a[k] * hv;
        gb1 += wh1b[k] * hv;
      }
      {
        const float fa = __shfl_xor(ga1, 32);
        const float ob = __shfl_xor(gb1, 32);
        c1 = sigf(fa) * c1 + al * sigf(ga1) * tanhf_(gb1);
        h1 = sigf(ob) * tanhf_(c1);
      }
    }
    al *= 0.333f;
  }
  if (l < 32) {
    grp[(size_t)t * 64 + l] = c0;        // group = concat(cc0, cc1)
    grp[(size_t)t * 64 + 32 + l] = c1;
  }
}

// ---------------------------------------------------------------------------
// K4: per-elevator out-LSTM recurrence. One block per elevator, 512 threads.
// thread t = gate index g in [0,512). OUT=128: cls = g>>7 (i,f,g,o).
// ---------------------------------------------------------------------------
__global__ __launch_bounds__(512) void k4_out(
    const float* __restrict__ pgo, const float* __restrict__ gg,
    const float* __restrict__ outh, const float* __restrict__ outc,
    const float* __restrict__ Whh, float* __restrict__ nohbuf, int B) {
  const int e = blockIdx.x;
  const int t = threadIdx.x;
  __shared__ float nhs[128], ncs[128], gbf[512];

  float w[128];
#pragma unroll
  for (int i = 0; i < 128; ++i) w[i] = Whh[(size_t)t * 128 + i];
  if (t < 128) { nhs[t] = outh[e * 128 + t]; ncs[t] = outc[e * 128 + t]; }
  __syncthreads();

  float pgv = pgo[(size_t)e * 512 + t] + gg[t];  // tt=0 prefetch
  for (int tt = 0; tt < B; ++tt) {
    float acc = pgv;
#pragma unroll
    for (int i = 0; i < 128; i += 4) {
      const float4 hv = *(const float4*)&nhs[i];
      acc += w[i] * hv.x + w[i + 1] * hv.y + w[i + 2] * hv.z + w[i + 3] * hv.w;
    }
    gbf[t] = ((t >> 7) == 2) ? tanhf_(acc) : sigf(acc);
    if (tt + 1 < B)
      pgv = pgo[((size_t)(tt + 1) * E_ + e) * 512 + t] + gg[(size_t)(tt + 1) * 512 + t];
    __syncthreads();
    if (t < 128) {
      const float iv = gbf[t], fv = gbf[128 + t], gv = gbf[256 + t], ov = gbf[384 + t];
      const float c = fv * ncs[t] + iv * gv;
      ncs[t] = c;
      const float h = ov * tanhf_(c);
      nhs[t] = h;
      nohbuf[((size_t)tt * E_ + e) * 128 + t] = h;
    }
    __syncthreads();
  }
}

// ---------------------------------------------------------------------------
// K5: heads. tar = softmax(noh@tarW^T + tb) [64], dir = softmax(noh@dirW^T + db) [3].
// One wave per row (t,e); tarW staged transposed in LDS; noh bcast via readlane.
// ---------------------------------------------------------------------------
__global__ __launch_bounds__(256) void k5_heads(
    const float* __restrict__ noh, const float* __restrict__ tarW,
    const float* __restrict__ tarb, const float* __restrict__ dirW,
    const float* __restrict__ dirb, float* __restrict__ out) {
  __shared__ float tw[128 * 64];
  __shared__ float tb[64];
  const int tid = threadIdx.x;
  for (int idx = tid; idx < 8192; idx += 256) {
    const int j = idx >> 7, k = idx & 127;
    tw[k * 64 + j] = tarW[idx];
  }
  if (tid < 64) tb[tid] = tarb[tid];
  __syncthreads();
  const int w = tid >> 6, l = tid & 63;
  const float db0 = dirb[0], db1 = dirb[1], db2 = dirb[2];

  for (int p = 0; p < 16; ++p) {
    const int row = blockIdx.x * 64 + p * 4 + w;
    const float na = noh[(size_t)row * 128 + l];
    const float nb = noh[(size_t)row * 128 + 64 + l];
    float acc = tb[l];
#pragma unroll
    for (int k = 0; k < 64; ++k) acc += tw[k * 64 + l] * lane_bcast(na, k);
#pragma unroll
    for (int k = 0; k < 64; ++k) acc += tw[(64 + k) * 64 + l] * lane_bcast(nb, k);
    // softmax over 64 lanes
    float m = acc;
#pragma unroll
    for (int s = 32; s; s >>= 1) m = fmaxf(m, __shfl_xor(m, s));
    const float ex = __expf(acc - m);
    float sm = ex;
#pragma unroll
    for (int s = 32; s; s >>= 1) sm += __shfl_xor(sm, s);
    out[(size_t)row * 67 + l] = ex / sm;
    // dir head: per-lane partials over k = l, l+64
    float d0 = dirW[l] * na + dirW[64 + l] * nb;
    float d1 = dirW[128 + l] * na + dirW[192 + l] * nb;
    float d2 = dirW[256 + l] * na + dirW[320 + l] * nb;
#pragma unroll
    for (int s = 32; s; s >>= 1) {
      d0 += __shfl_xor(d0, s);
      d1 += __shfl_xor(d1, s);
      d2 += __shfl_xor(d2, s);
    }
    d0 += db0; d1 += db1; d2 += db2;
    const float dm = fmaxf(d0, fmaxf(d1, d2));
    const float e0 = __expf(d0 - dm), e1 = __expf(d1 - dm), e2 = __expf(d2 - dm);
    const float ds = e0 + e1 + e2;
    if (l < 3) out[(size_t)row * 67 + 64 + l] = (l == 0 ? e0 : (l == 1 ? e1 : e2)) / ds;
  }
}

// ---------------------------------------------------------------------------
extern "C" void kernel_launch(void* const* d_in, const int* in_sizes, int n_in,
                              void* d_out, int out_size, void* d_ws, size_t ws_size,
                              hipStream_t stream) {
  const float* features = (const float*)d_in[0];
  const float* pre_h    = (const float*)d_in[1];
  const float* pre_c    = (const float*)d_in[2];
  const float* out_h    = (const float*)d_in[3];
  const float* out_c    = (const float*)d_in[4];
  const float* pre_Wih0 = (const float*)d_in[5];
  const float* pre_Whh0 = (const float*)d_in[6];
  const float* pre_bih0 = (const float*)d_in[7];
  const float* pre_bhh0 = (const float*)d_in[8];
  const float* pre_Wih1 = (const float*)d_in[9];
  const float* pre_Whh1 = (const float*)d_in[10];
  const float* pre_bih1 = (const float*)d_in[11];
  const float* pre_bhh1 = (const float*)d_in[12];
  const float* fc_W     = (const float*)d_in[13];
  const float* fc_b     = (const float*)d_in[14];
  const float* comm_Wih0 = (const float*)d_in[15];
  const float* comm_Whh0 = (const float*)d_in[16];
  const float* comm_bih0 = (const float*)d_in[17];
  const float* comm_bhh0 = (const float*)d_in[18];
  const float* comm_Wih1 = (const float*)d_in[19];
  const float* comm_Whh1 = (const float*)d_in[20];
  const float* comm_bih1 = (const float*)d_in[21];
  const float* comm_bhh1 = (const float*)d_in[22];
  const float* out_Wih  = (const float*)d_in[23];
  const float* out_Whh  = (const float*)d_in[24];
  const float* out_bih  = (const float*)d_in[25];
  const float* out_bhh  = (const float*)d_in[26];
  const float* tar_W    = (const float*)d_in[27];
  const float* tar_b    = (const float*)d_in[28];
  const float* dir_W    = (const float*)d_in[29];
  const float* dir_b    = (const float*)d_in[30];

  const int B = in_sizes[0] / (E_ * F_);   // 2048
  float* ws = (float*)d_ws;
  float* pg0 = ws;                                  // [B*16, 256]
  float* pgo = pg0 + (size_t)B * E_ * 256;          // [B*16, 512]
  float* xbf = pgo + (size_t)B * E_ * 512;          // [B*16, 64]
  float* gih = xbf + (size_t)B * E_ * 64;           // [B*16, 128]
  float* grp = gih + (size_t)B * E_ * 128;          // [B, 64]
  float* gg  = grp + (size_t)B * 64;                // [B, 512]
  float* noh = gg + (size_t)B * 512;                // [B*16, 128]
  (void)ws_size; (void)n_in; (void)out_size;

  const int MB = B * E_ / 64;  // 512 m-blocks for the [B*16, K] GEMMs

  // G1: pre-LSTM layer0 input projection (+ both biases)
  gemm_k<<<dim3(MB, 2), 256, 0, stream>>>(features, 128, pre_Wih0, 128, 0,
                                          pre_bih0, pre_bhh0, pg0, 256, 128);
  // G2: out-LSTM feat-half input projection (+ both biases)
  gemm_k<<<dim3(MB, 4), 256, 0, stream>>>(features, 128, out_Wih, 192, 64,
                                          out_bih, out_bhh, pgo, 512, 128);
  // K2: pre recurrence (writes x)
  k2_pre<<<E_, 512, 0, stream>>>(pg0, pre_h, pre_c, pre_Whh0, pre_Wih1, pre_Whh1,
                                 pre_bih1, pre_bhh1, fc_W, fc_b, xbf, B);
  // G4: comm layer0 input projection (+ both biases)
  gemm_k<<<dim3(MB, 1), 256, 0, stream>>>(xbf, 64, comm_Wih0, 64, 0,
                                          comm_bih0, comm_bhh0, gih, 128, 64);
  // K3: comm chains (writes group cell states)
  k3_comm<<<B / 4, 256, 0, stream>>>(gih, comm_Whh0, comm_Wih1, comm_Whh1,
                                     comm_bih1, comm_bhh1, grp, B);
  // G6: out-LSTM group-half input projection (no bias; already in pgo)
  gemm_k<<<dim3(B / 64, 4), 256, 0, stream>>>(grp, 64, out_Wih, 192, 0,
                                              nullptr, nullptr, gg, 512, 64);
  // K4: out recurrence (writes noh)
  k4_out<<<E_, 512, 0, stream>>>(pgo, gg, out_h, out_c, out_Whh, noh, B);
  // K5: heads + softmax -> d_out [B,16,67]
  k5_heads<<<B * E_ / 64, 256, 0, stream>>>(noh, tar_W, tar_b, dir_W, dir_b,
                                            (float*)d_out);
}

// Round 2
// 4675.174 us; speedup vs baseline: 1.2371x; 1.2371x over previous
//
#include <hip/hip_runtime.h>
#include <hip/hip_bf16.h>

// alphaLSTMNetwork: B=2048 sequential steps, E=16 elevators.
//   G1: pg0  = feat @ pre_Wih0^T + bih0 + bhh0            [B*16, 256]  (parallel)
//   G2: pgo  = feat @ out_Wih[:,64:]^T + bih + bhh        [B*16, 512]  (parallel)
//   K2: per-elevator 2-layer pre-LSTM + fc recurrence     (16 blocks, seq over t)
//   G4: gih  = x @ comm_Wih0^T + bih0 + bhh0              [B*16, 128]  (parallel)
//   K3: comm alpha-LSTM, 48 micro-steps, state resets/t   (1 wave per t, parallel)
//   G6: gg   = group @ out_Wih[:,:64]^T                   [B, 512]     (parallel)
//   K4: per-elevator out-LSTM recurrence                  (16 blocks, seq over t)
//   K5: heads (tar/dir softmax)                           (parallel)
// R2: recurrences rebuilt around v_dot2_f32_f16 (fp16 weights/h, fp32 acc),
//     register-resident weights, wave-uniform LDS h-broadcast, depth-2 prefetch,
//     no shuffles, 4 waves/block.

#define E_ 16
#define F_ 128

typedef int i4 __attribute__((ext_vector_type(4)));
typedef _Float16 hf;
typedef hf hf2 __attribute__((ext_vector_type(2)));

__device__ __forceinline__ float sigf(float x) { return 1.0f / (1.0f + __expf(-x)); }
__device__ __forceinline__ float tanhf_(float x) {
  float e = __expf(2.0f * x);
  return 1.0f - 2.0f / (e + 1.0f);
}
__device__ __forceinline__ float lane_bcast(float v, int k) {
  return __int_as_float(__builtin_amdgcn_readlane(__float_as_int(v), k));
}
__device__ __forceinline__ float fdot2(int a, int b, float c) {
#if __has_builtin(__builtin_amdgcn_fdot2)
  return __builtin_amdgcn_fdot2(__builtin_bit_cast(hf2, a),
                                __builtin_bit_cast(hf2, b), c, false);
#else
  float d;
  asm("v_dot2_f32_f16 %0, %1, %2, %3" : "=v"(d) : "v"(a), "v"(b), "v"(c));
  return d;
#endif
}

// ---------------------------------------------------------------------------
// fp32 -> fp16 weight conversion (one-time per call, tiny)
// ---------------------------------------------------------------------------
__global__ void f2h_kernel(const float* __restrict__ src, hf* __restrict__ dst, int n) {
  int i = blockIdx.x * 256 + threadIdx.x;
  if (i < n) dst[i] = (hf)src[i];
}

// ---------------------------------------------------------------------------
// Generic skinny GEMM: C[m,n] = sum_k A[m,k]*W[n, co+k] (+b1[n]+b2[n])
// Tile 64m x 128n, KC=64, block 256, 4x8 microtile.
// ---------------------------------------------------------------------------
__global__ __launch_bounds__(256) void gemm_k(
    const float* __restrict__ A, int lda,
    const float* __restrict__ W, int ldw, int co,
    const float* __restrict__ b1, const float* __restrict__ b2,
    float* __restrict__ C, int N, int K) {
  __shared__ float As[64 * 65];
  __shared__ float Ws[128 * 65];
  const int tid = threadIdx.x;
  const int m0 = blockIdx.x * 64;
  const int n0 = blockIdx.y * 128;
  const int rr = tid >> 4;
  const int c4 = (tid & 15) << 2;
  const int tm = tid >> 4;
  const int tn = tid & 15;

  float acc[4][8];
#pragma unroll
  for (int i = 0; i < 4; ++i)
#pragma unroll
    for (int j = 0; j < 8; ++j) acc[i][j] = 0.0f;

  for (int kk = 0; kk < K; kk += 64) {
#pragma unroll
    for (int p = 0; p < 4; ++p) {
      const int r = rr + p * 16;
      const float4 v = *(const float4*)(A + (size_t)(m0 + r) * lda + kk + c4);
      float* dst = &As[r * 65 + c4];
      dst[0] = v.x; dst[1] = v.y; dst[2] = v.z; dst[3] = v.w;
    }
#pragma unroll
    for (int p = 0; p < 8; ++p) {
      const int n = rr + p * 16;
      const float4 v = *(const float4*)(W + (size_t)(n0 + n) * ldw + co + kk + c4);
      float* dst = &Ws[n * 65 + c4];
      dst[0] = v.x; dst[1] = v.y; dst[2] = v.z; dst[3] = v.w;
    }
    __syncthreads();
#pragma unroll 4
    for (int k = 0; k < 64; ++k) {
      float a[4], wv[8];
#pragma unroll
      for (int i = 0; i < 4; ++i) a[i] = As[(tm * 4 + i) * 65 + k];
#pragma unroll
      for (int j = 0; j < 8; ++j) wv[j] = Ws[(tn * 8 + j) * 65 + k];
#pragma unroll
      for (int i = 0; i < 4; ++i)
#pragma unroll
        for (int j = 0; j < 8; ++j) acc[i][j] += a[i] * wv[j];
    }
    __syncthreads();
  }
#pragma unroll
  for (int i = 0; i < 4; ++i) {
    const int m = m0 + tm * 4 + i;
#pragma unroll
    for (int j = 0; j < 8; ++j) {
      const int n = n0 + tn * 8 + j;
      float v = acc[i][j];
      if (b1) v += b1[n];
      if (b2) v += b2[n];
      C[(size_t)m * N + n] = v;
    }
  }
}

// ---------------------------------------------------------------------------
// K2: per-elevator pre-LSTM (2 layers) + fc. 16 blocks x 256 threads (4 waves).
// Thread t owns gate row t (class q=t>>6, elem j=t&63). fp16 weights in regs
// (packed dwords), h in LDS as fp16, v_dot2_f32_f16 dots, 4 barriers/step.
// class0 owns c0[j]/h0 write, class1 owns c1[j]/h1, class2 does fc.
// ---------------------------------------------------------------------------
__global__ __launch_bounds__(256) void k2_pre(
    const float* __restrict__ pg0, const float* __restrict__ preh,
    const float* __restrict__ prec,
    const hf* __restrict__ hWhh0, const hf* __restrict__ hWih1,
    const hf* __restrict__ hWhh1, const hf* __restrict__ hfcW,
    const float* __restrict__ bih1, const float* __restrict__ bhh1,
    const float* __restrict__ fcb, float* __restrict__ xout, int B) {
  const int e = blockIdx.x, t = threadIdx.x;
  const int q = t >> 6, j = t & 63;
  __shared__ __align__(16) hf h0s[64];
  __shared__ __align__(16) hf h1s[64];
  __shared__ float gb0[256], gb1[256];

  int w0[32], wi1[32], wh1[32], wf[32];
  {
    const i4* p0 = (const i4*)(hWhh0 + t * 64);
    const i4* p1 = (const i4*)(hWih1 + t * 64);
    const i4* p2 = (const i4*)(hWhh1 + t * 64);
    const i4* pf = (const i4*)(hfcW + j * 64);
#pragma unroll
    for (int i = 0; i < 8; ++i) {
      i4 a = p0[i]; w0[4*i]=a.x;  w0[4*i+1]=a.y;  w0[4*i+2]=a.z;  w0[4*i+3]=a.w;
      i4 b = p1[i]; wi1[4*i]=b.x; wi1[4*i+1]=b.y; wi1[4*i+2]=b.z; wi1[4*i+3]=b.w;
      i4 c = p2[i]; wh1[4*i]=c.x; wh1[4*i+1]=c.y; wh1[4*i+2]=c.z; wh1[4*i+3]=c.w;
      i4 d = pf[i]; wf[4*i]=d.x;  wf[4*i+1]=d.y;  wf[4*i+2]=d.z;  wf[4*i+3]=d.w;
    }
  }
  const float b1v = bih1[t] + bhh1[t];
  const float fbv = fcb[j];
  float c0 = 0.f, c1 = 0.f;
  if (q == 0) { c0 = prec[e * 128 + j];      h0s[j] = (hf)preh[e * 128 + j]; }
  if (q == 1) { c1 = prec[e * 128 + 64 + j]; h1s[j] = (hf)preh[e * 128 + 64 + j]; }
  __syncthreads();

  const float* pgp = pg0 + (size_t)e * 256 + t;  // + tt*4096
  float pgA = pgp[0];
  float pgB = (B > 1) ? pgp[4096] : 0.f;
  const i4* hp0 = (const i4*)h0s;
  const i4* hp1 = (const i4*)h1s;

  for (int tt = 0; tt < B; ++tt) {
    float pgC = (tt + 2 < B) ? pgp[(size_t)(tt + 2) * 4096] : 0.f;
    // ---- layer0 gates: pg0 already has x-part + both biases
    float a0 = 0.f, a1 = 0.f, a2 = 0.f, a3 = 0.f;
#pragma unroll
    for (int i = 0; i < 8; ++i) {
      i4 h = hp0[i];
      a0 = fdot2(w0[4*i],   h.x, a0); a1 = fdot2(w0[4*i+1], h.y, a1);
      a2 = fdot2(w0[4*i+2], h.z, a2); a3 = fdot2(w0[4*i+3], h.w, a3);
    }
    {
      const float pre = (a0 + a1) + (a2 + a3) + pgA;
      gb0[t] = (q == 2) ? tanhf_(pre) : sigf(pre);
    }
    __syncthreads();
    if (q == 0) {
      const float iv = gb0[j], fv = gb0[64+j], gv = gb0[128+j], ov = gb0[192+j];
      c0 = fv * c0 + iv * gv;
      h0s[j] = (hf)(ov * tanhf_(c0));
    }
    __syncthreads();
    // ---- layer1 gates: h0 @ Wih1^T + h1 @ Whh1^T + b
    a0 = a1 = a2 = a3 = 0.f;
#pragma unroll
    for (int i = 0; i < 8; ++i) {
      i4 h = hp0[i];
      a0 = fdot2(wi1[4*i],   h.x, a0); a1 = fdot2(wi1[4*i+1], h.y, a1);
      a2 = fdot2(wi1[4*i+2], h.z, a2); a3 = fdot2(wi1[4*i+3], h.w, a3);
    }
#pragma unroll
    for (int i = 0; i < 8; ++i) {
      i4 h = hp1[i];
      a0 = fdot2(wh1[4*i],   h.x, a0); a1 = fdot2(wh1[4*i+1], h.y, a1);
      a2 = fdot2(wh1[4*i+2], h.z, a2); a3 = fdot2(wh1[4*i+3], h.w, a3);
    }
    {
      const float pre = (a0 + a1) + (a2 + a3) + b1v;
      gb1[t] = (q == 2) ? tanhf_(pre) : sigf(pre);
    }
    __syncthreads();
    if (q == 1) {
      const float iv = gb1[j], fv = gb1[64+j], gv = gb1[128+j], ov = gb1[192+j];
      c1 = fv * c1 + iv * gv;
      h1s[j] = (hf)(ov * tanhf_(c1));
    }
    __syncthreads();
    // ---- fc + leaky_relu(0.05) on class-2 threads (runs alongside next L0)
    if (q == 2) {
      float b0 = 0.f, bb1 = 0.f, b2 = 0.f, b3 = 0.f;
#pragma unroll
      for (int i = 0; i < 8; ++i) {
        i4 h = hp1[i];
        b0 = fdot2(wf[4*i],   h.x, b0); bb1 = fdot2(wf[4*i+1], h.y, bb1);
        b2 = fdot2(wf[4*i+2], h.z, b2); b3 = fdot2(wf[4*i+3], h.w, b3);
      }
      const float xv = (b0 + bb1) + (b2 + b3) + fbv;
      xout[((size_t)tt * E_ + e) * 64 + j] = (xv > 0.f) ? xv : 0.05f * xv;
    }
    pgA = pgB; pgB = pgC;
  }
}

// ---------------------------------------------------------------------------
// K3: communication alpha-LSTM. One wave per timestep t (state resets each t).
// ---------------------------------------------------------------------------
__global__ __launch_bounds__(256) void k3_comm(
    const float* __restrict__ gih0, const float* __restrict__ Whh0,
    const float* __restrict__ Wih1, const float* __restrict__ Whh1,
    const float* __restrict__ bih1, const float* __restrict__ bhh1,
    float* __restrict__ grp, int B) {
  const int w = threadIdx.x >> 6;
  const int l = threadIdx.x & 63;
  const int t = blockIdx.x * 4 + w;

  float wh0a[32], wh0b[32], wi1a[32], wi1b[32], wh1a[32], wh1b[32];
#pragma unroll
  for (int i = 0; i < 32; ++i) {
    wh0a[i] = Whh0[l * 32 + i];         wh0b[i] = Whh0[(l + 64) * 32 + i];
    wi1a[i] = Wih1[l * 32 + i];         wi1b[i] = Wih1[(l + 64) * 32 + i];
    wh1a[i] = Whh1[l * 32 + i];         wh1b[i] = Whh1[(l + 64) * 32 + i];
  }
  const float cb1a = bih1[l] + bhh1[l];
  const float cb1b = bih1[l + 64] + bhh1[l + 64];

  float h0 = 0.0f, c0 = 0.0f, h1 = 0.0f, c1 = 0.0f;
  float al = 1.0f;
  const float* gbase = gih0 + (size_t)t * (E_ * 128);
  for (int r = 0; r < 3; ++r) {
    for (int e = 0; e < E_; ++e) {
      float ga = gbase[e * 128 + l];
      float gb = gbase[e * 128 + l + 64];
#pragma unroll
      for (int k = 0; k < 32; ++k) {
        const float hv = lane_bcast(h0, k);
        ga += wh0a[k] * hv;
        gb += wh0b[k] * hv;
      }
      {
        const float fa = __shfl_xor(ga, 32);
        const float ob = __shfl_xor(gb, 32);
        c0 = sigf(fa) * c0 + al * sigf(ga) * tanhf_(gb);
        h0 = sigf(ob) * tanhf_(c0);
      }
      float ga1 = cb1a, gb1 = cb1b;
#pragma unroll
      for (int k = 0; k < 32; ++k) {
        const float hv = lane_bcast(h0, k);
        ga1 += wi1a[k] * hv;
        gb1 += wi1b[k] * hv;
      }
#pragma unroll
      for (int k = 0; k < 32; ++k) {
        const float hv = lane_bcast(h1, k);
        ga1 += wh1a[k] * hv;
        gb1 += wh1b[k] * hv;
      }
      {
        const float fa = __shfl_xor(ga1, 32);
        const float ob = __shfl_xor(gb1, 32);
        c1 = sigf(fa) * c1 + al * sigf(ga1) * tanhf_(gb1);
        h1 = sigf(ob) * tanhf_(c1);
      }
    }
    al *= 0.333f;
  }
  if (l < 32) {
    grp[(size_t)t * 64 + l] = c0;
    grp[(size_t)t * 64 + 32 + l] = c1;
  }
}

// ---------------------------------------------------------------------------
// K4: per-elevator out-LSTM. 16 blocks x 256 threads (4 waves).
// Thread t owns gates t and t+256 (fp16 weight rows in regs, 128 dot2/step).
// h (fp16) broadcast from LDS; 2 barriers/step; depth-2 prefetch of pgo+gg.
// ---------------------------------------------------------------------------
__global__ __launch_bounds__(256) void k4_out(
    const float* __restrict__ pgo, const float* __restrict__ gg,
    const float* __restrict__ outh, const float* __restrict__ outc,
    const hf* __restrict__ hWo, float* __restrict__ noh, int B) {
  const int e = blockIdx.x, t = threadIdx.x;
  __shared__ __align__(16) hf nhs[128];
  __shared__ float gbf[512];

  int wA[64], wB[64];
  {
    const i4* pa = (const i4*)(hWo + (size_t)t * 128);
    const i4* pb = (const i4*)(hWo + (size_t)(t + 256) * 128);
#pragma unroll
    for (int i = 0; i < 16; ++i) {
      i4 a = pa[i]; wA[4*i]=a.x; wA[4*i+1]=a.y; wA[4*i+2]=a.z; wA[4*i+3]=a.w;
      i4 b = pb[i]; wB[4*i]=b.x; wB[4*i+1]=b.y; wB[4*i+2]=b.z; wB[4*i+3]=b.w;
    }
  }
  float c = 0.f;
  if (t < 128) { c = outc[e * 128 + t]; nhs[t] = (hf)outh[e * 128 + t]; }
  __syncthreads();

  const float* pgoA = pgo + (size_t)e * 512 + t;  // + tt*8192; gate B at +256
  const float* ggA  = gg + t;                     // + tt*512
  float fa0 = pgoA[0] + ggA[0];
  float fb0 = pgoA[256] + ggA[256];
  float fa1 = (B > 1) ? pgoA[8192] + ggA[512] : 0.f;
  float fb1 = (B > 1) ? pgoA[8192 + 256] + ggA[512 + 256] : 0.f;
  const i4* hp = (const i4*)nhs;

  for (int tt = 0; tt < B; ++tt) {
    float fa2 = 0.f, fb2 = 0.f;
    if (tt + 2 < B) {
      fa2 = pgoA[(size_t)(tt + 2) * 8192] + ggA[(size_t)(tt + 2) * 512];
      fb2 = pgoA[(size_t)(tt + 2) * 8192 + 256] + ggA[(size_t)(tt + 2) * 512 + 256];
    }
    float a0 = 0.f, a1 = 0.f, b0 = 0.f, b1 = 0.f;
#pragma unroll
    for (int i = 0; i < 16; ++i) {
      i4 h = hp[i];
      a0 = fdot2(wA[4*i],   h.x, a0); a1 = fdot2(wA[4*i+1], h.y, a1);
      a0 = fdot2(wA[4*i+2], h.z, a0); a1 = fdot2(wA[4*i+3], h.w, a1);
      b0 = fdot2(wB[4*i],   h.x, b0); b1 = fdot2(wB[4*i+1], h.y, b1);
      b0 = fdot2(wB[4*i+2], h.z, b0); b1 = fdot2(wB[4*i+3], h.w, b1);
    }
    const float gA = a0 + a1 + fa0;                      // gates 0..255: i|f -> sig
    const float gB = b0 + b1 + fb0;                      // gates 256..511: g|o
    gbf[t] = sigf(gA);
    gbf[t + 256] = (t < 128) ? tanhf_(gB) : sigf(gB);
    __syncthreads();
    if (t < 128) {
      const float iv = gbf[t], fv = gbf[128 + t], gv = gbf[256 + t], ov = gbf[384 + t];
      c = fv * c + iv * gv;
      const float h = ov * tanhf_(c);
      nhs[t] = (hf)h;
      noh[((size_t)tt * E_ + e) * 128 + t] = h;
    }
    __syncthreads();
    fa0 = fa1; fb0 = fb1; fa1 = fa2; fb1 = fb2;
  }
}

// ---------------------------------------------------------------------------
// K5: heads. tar = softmax(noh@tarW^T + tb) [64], dir = softmax(noh@dirW^T + db) [3].
// ---------------------------------------------------------------------------
__global__ __launch_bounds__(256) void k5_heads(
    const float* __restrict__ noh, const float* __restrict__ tarW,
    const float* __restrict__ tarb, const float* __restrict__ dirW,
    const float* __restrict__ dirb, float* __restrict__ out) {
  __shared__ float tw[128 * 64];
  __shared__ float tb[64];
  const int tid = threadIdx.x;
  for (int idx = tid; idx < 8192; idx += 256) {
    const int j = idx >> 7, k = idx & 127;
    tw[k * 64 + j] = tarW[idx];
  }
  if (tid < 64) tb[tid] = tarb[tid];
  __syncthreads();
  const int w = tid >> 6, l = tid & 63;
  const float db0 = dirb[0], db1 = dirb[1], db2 = dirb[2];

  for (int p = 0; p < 16; ++p) {
    const int row = blockIdx.x * 64 + p * 4 + w;
    const float na = noh[(size_t)row * 128 + l];
    const float nb = noh[(size_t)row * 128 + 64 + l];
    float acc = tb[l];
#pragma unroll
    for (int k = 0; k < 64; ++k) acc += tw[k * 64 + l] * lane_bcast(na, k);
#pragma unroll
    for (int k = 0; k < 64; ++k) acc += tw[(64 + k) * 64 + l] * lane_bcast(nb, k);
    float m = acc;
#pragma unroll
    for (int s = 32; s; s >>= 1) m = fmaxf(m, __shfl_xor(m, s));
    const float ex = __expf(acc - m);
    float sm = ex;
#pragma unroll
    for (int s = 32; s; s >>= 1) sm += __shfl_xor(sm, s);
    out[(size_t)row * 67 + l] = ex / sm;
    float d0 = dirW[l] * na + dirW[64 + l] * nb;
    float d1 = dirW[128 + l] * na + dirW[192 + l] * nb;
    float d2 = dirW[256 + l] * na + dirW[320 + l] * nb;
#pragma unroll
    for (int s = 32; s; s >>= 1) {
      d0 += __shfl_xor(d0, s);
      d1 += __shfl_xor(d1, s);
      d2 += __shfl_xor(d2, s);
    }
    d0 += db0; d1 += db1; d2 += db2;
    const float dm = fmaxf(d0, fmaxf(d1, d2));
    const float e0 = __expf(d0 - dm), e1 = __expf(d1 - dm), e2 = __expf(d2 - dm);
    const float ds = e0 + e1 + e2;
    if (l < 3) out[(size_t)row * 67 + 64 + l] = (l == 0 ? e0 : (l == 1 ? e1 : e2)) / ds;
  }
}

// ---------------------------------------------------------------------------
extern "C" void kernel_launch(void* const* d_in, const int* in_sizes, int n_in,
                              void* d_out, int out_size, void* d_ws, size_t ws_size,
                              hipStream_t stream) {
  const float* features = (const float*)d_in[0];
  const float* pre_h    = (const float*)d_in[1];
  const float* pre_c    = (const float*)d_in[2];
  const float* out_h    = (const float*)d_in[3];
  const float* out_c    = (const float*)d_in[4];
  const float* pre_Wih0 = (const float*)d_in[5];
  const float* pre_Whh0 = (const float*)d_in[6];
  const float* pre_bih0 = (const float*)d_in[7];
  const float* pre_bhh0 = (const float*)d_in[8];
  const float* pre_Wih1 = (const float*)d_in[9];
  const float* pre_Whh1 = (const float*)d_in[10];
  const float* pre_bih1 = (const float*)d_in[11];
  const float* pre_bhh1 = (const float*)d_in[12];
  const float* fc_W     = (const float*)d_in[13];
  const float* fc_b     = (const float*)d_in[14];
  const float* comm_Wih0 = (const float*)d_in[15];
  const float* comm_Whh0 = (const float*)d_in[16];
  const float* comm_bih0 = (const float*)d_in[17];
  const float* comm_bhh0 = (const float*)d_in[18];
  const float* comm_Wih1 = (const float*)d_in[19];
  const float* comm_Whh1 = (const float*)d_in[20];
  const float* comm_bih1 = (const float*)d_in[21];
  const float* comm_bhh1 = (const float*)d_in[22];
  const float* out_Wih  = (const float*)d_in[23];
  const float* out_Whh  = (const float*)d_in[24];
  const float* out_bih  = (const float*)d_in[25];
  const float* out_bhh  = (const float*)d_in[26];
  const float* tar_W    = (const float*)d_in[27];
  const float* tar_b    = (const float*)d_in[28];
  const float* dir_W    = (const float*)d_in[29];
  const float* dir_b    = (const float*)d_in[30];

  const int B = in_sizes[0] / (E_ * F_);   // 2048
  float* ws = (float*)d_ws;
  float* pg0 = ws;                                  // [B*16, 256]
  float* pgo = pg0 + (size_t)B * E_ * 256;          // [B*16, 512]
  float* xbf = pgo + (size_t)B * E_ * 512;          // [B*16, 64]
  float* gih = xbf + (size_t)B * E_ * 64;           // [B*16, 128]
  float* grp = gih + (size_t)B * E_ * 128;          // [B, 64]
  float* gg  = grp + (size_t)B * 64;                // [B, 512]
  float* noh = gg + (size_t)B * 512;                // [B*16, 128]
  hf* hWhh0 = (hf*)(noh + (size_t)B * E_ * 128);    // [256*64]
  hf* hWih1 = hWhh0 + 256 * 64;                     // [256*64]
  hf* hWhh1 = hWih1 + 256 * 64;                     // [256*64]
  hf* hfcW  = hWhh1 + 256 * 64;                     // [64*64]
  hf* hWo   = hfcW + 64 * 64;                       // [512*128]
  (void)ws_size; (void)n_in; (void)out_size;

  // W0: fp32 -> fp16 weight packs for the recurrence kernels
  f2h_kernel<<<(256 * 64 + 255) / 256, 256, 0, stream>>>(pre_Whh0, hWhh0, 256 * 64);
  f2h_kernel<<<(256 * 64 + 255) / 256, 256, 0, stream>>>(pre_Wih1, hWih1, 256 * 64);
  f2h_kernel<<<(256 * 64 + 255) / 256, 256, 0, stream>>>(pre_Whh1, hWhh1, 256 * 64);
  f2h_kernel<<<(64 * 64 + 255) / 256, 256, 0, stream>>>(fc_W, hfcW, 64 * 64);
  f2h_kernel<<<(512 * 128 + 255) / 256, 256, 0, stream>>>(out_Whh, hWo, 512 * 128);

  const int MB = B * E_ / 64;

  // G1: pre-LSTM layer0 input projection (+ both biases)
  gemm_k<<<dim3(MB, 2), 256, 0, stream>>>(features, 128, pre_Wih0, 128, 0,
                                          pre_bih0, pre_bhh0, pg0, 256, 128);
  // G2: out-LSTM feat-half input projection (+ both biases)
  gemm_k<<<dim3(MB, 4), 256, 0, stream>>>(features, 128, out_Wih, 192, 64,
                                          out_bih, out_bhh, pgo, 512, 128);
  // K2: pre recurrence (writes x)
  k2_pre<<<E_, 256, 0, stream>>>(pg0, pre_h, pre_c, hWhh0, hWih1, hWhh1, hfcW,
                                 pre_bih1, pre_bhh1, fc_b, xbf, B);
  // G4: comm layer0 input projection (+ both biases)
  gemm_k<<<dim3(MB, 1), 256, 0, stream>>>(xbf, 64, comm_Wih0, 64, 0,
                                          comm_bih0, comm_bhh0, gih, 128, 64);
  // K3: comm chains (writes group cell states)
  k3_comm<<<B / 4, 256, 0, stream>>>(gih, comm_Whh0, comm_Wih1, comm_Whh1,
                                     comm_bih1, comm_bhh1, grp, B);
  // G6: out-LSTM group-half input projection
  gemm_k<<<dim3(B / 64, 4), 256, 0, stream>>>(grp, 64, out_Wih, 192, 0,
                                              nullptr, nullptr, gg, 512, 64);
  // K4: out recurrence (writes noh)
  k4_out<<<E_, 256, 0, stream>>>(pgo, gg, out_h, out_c, hWo, noh, B);
  // K5: heads + softmax -> d_out [B,16,67]
  k5_heads<<<B * E_ / 64, 256, 0, stream>>>(noh, tar_W, tar_b, dir_W, dir_b,
                                            (float*)d_out);
}

// Round 3
// 3198.734 us; speedup vs baseline: 1.8082x; 1.4616x over previous
//
#include <hip/hip_runtime.h>
#include <hip/hip_bf16.h>

// alphaLSTMNetwork: B=2048 sequential steps, E=16 elevators.
//   G1: pg0  = feat @ pre_Wih0^T + bih0 + bhh0            [B*16, 256]  (parallel)
//   G2: pgo  = feat @ out_Wih[:,64:]^T + bih + bhh        [B*16, 512]  (parallel)
//   K2: per-elevator 2-layer pre-LSTM + fc recurrence     (16 blocks, seq over t)
//   G4: gih  = x @ comm_Wih0^T + bih0 + bhh0              [B*16, 128]  (parallel)
//   K3: comm alpha-LSTM, 48 micro-steps, state resets/t   (1 wave per t, parallel)
//   G6: gg   = group @ out_Wih[:,:64]^T                   [B, 512]     (parallel)
//   K4: per-elevator out-LSTM recurrence                  (16 blocks, seq over t)
//   K5: heads (tar/dir softmax)                           (parallel)
// R3: k2/k4 restructured to ONE barrier per step:
//  - 4 gates of an element live in 4 lanes of one wave (cls = lane>>4);
//    gate gather via shfl_xor(32) then shfl_xor(16) — no LDS gate buffers.
//  - k2 pipelines L0(n) / L1(n-1) / fc(n-2) across wave groups A(4w)/B(4w)/C(1w)
//    with double-buffered h0s/h1s in LDS.
//  - k4: 8 waves, elem j = wave*16+sub, 64 dot2/thread, raw depth-2 prefetch.

#define E_ 16
#define F_ 128

typedef int i4 __attribute__((ext_vector_type(4)));
typedef _Float16 hf;
typedef hf hf2 __attribute__((ext_vector_type(2)));

__device__ __forceinline__ float sigf(float x) { return 1.0f / (1.0f + __expf(-x)); }
__device__ __forceinline__ float tanhf_(float x) {
  float e = __expf(2.0f * x);
  return 1.0f - 2.0f / (e + 1.0f);
}
__device__ __forceinline__ float lane_bcast(float v, int k) {
  return __int_as_float(__builtin_amdgcn_readlane(__float_as_int(v), k));
}
__device__ __forceinline__ float fdot2(int a, int b, float c) {
#if __has_builtin(__builtin_amdgcn_fdot2)
  return __builtin_amdgcn_fdot2(__builtin_bit_cast(hf2, a),
                                __builtin_bit_cast(hf2, b), c, false);
#else
  float d;
  asm("v_dot2_f32_f16 %0, %1, %2, %3" : "=v"(d) : "v"(a), "v"(b), "v"(c));
  return d;
#endif
}

// ---------------------------------------------------------------------------
// fp32 -> fp16 weight conversion (one-time per call, tiny)
// ---------------------------------------------------------------------------
__global__ void f2h_kernel(const float* __restrict__ src, hf* __restrict__ dst, int n) {
  int i = blockIdx.x * 256 + threadIdx.x;
  if (i < n) dst[i] = (hf)src[i];
}

// ---------------------------------------------------------------------------
// Generic skinny GEMM: C[m,n] = sum_k A[m,k]*W[n, co+k] (+b1[n]+b2[n])
// ---------------------------------------------------------------------------
__global__ __launch_bounds__(256) void gemm_k(
    const float* __restrict__ A, int lda,
    const float* __restrict__ W, int ldw, int co,
    const float* __restrict__ b1, const float* __restrict__ b2,
    float* __restrict__ C, int N, int K) {
  __shared__ float As[64 * 65];
  __shared__ float Ws[128 * 65];
  const int tid = threadIdx.x;
  const int m0 = blockIdx.x * 64;
  const int n0 = blockIdx.y * 128;
  const int rr = tid >> 4;
  const int c4 = (tid & 15) << 2;
  const int tm = tid >> 4;
  const int tn = tid & 15;

  float acc[4][8];
#pragma unroll
  for (int i = 0; i < 4; ++i)
#pragma unroll
    for (int j = 0; j < 8; ++j) acc[i][j] = 0.0f;

  for (int kk = 0; kk < K; kk += 64) {
#pragma unroll
    for (int p = 0; p < 4; ++p) {
      const int r = rr + p * 16;
      const float4 v = *(const float4*)(A + (size_t)(m0 + r) * lda + kk + c4);
      float* dst = &As[r * 65 + c4];
      dst[0] = v.x; dst[1] = v.y; dst[2] = v.z; dst[3] = v.w;
    }
#pragma unroll
    for (int p = 0; p < 8; ++p) {
      const int n = rr + p * 16;
      const float4 v = *(const float4*)(W + (size_t)(n0 + n) * ldw + co + kk + c4);
      float* dst = &Ws[n * 65 + c4];
      dst[0] = v.x; dst[1] = v.y; dst[2] = v.z; dst[3] = v.w;
    }
    __syncthreads();
#pragma unroll 4
    for (int k = 0; k < 64; ++k) {
      float a[4], wv[8];
#pragma unroll
      for (int i = 0; i < 4; ++i) a[i] = As[(tm * 4 + i) * 65 + k];
#pragma unroll
      for (int j = 0; j < 8; ++j) wv[j] = Ws[(tn * 8 + j) * 65 + k];
#pragma unroll
      for (int i = 0; i < 4; ++i)
#pragma unroll
        for (int j = 0; j < 8; ++j) acc[i][j] += a[i] * wv[j];
    }
    __syncthreads();
  }
#pragma unroll
  for (int i = 0; i < 4; ++i) {
    const int m = m0 + tm * 4 + i;
#pragma unroll
    for (int j = 0; j < 8; ++j) {
      const int n = n0 + tn * 8 + j;
      float v = acc[i][j];
      if (b1) v += b1[n];
      if (b2) v += b2[n];
      C[(size_t)m * N + n] = v;
    }
  }
}

// ---------------------------------------------------------------------------
// K2: per-elevator pre-LSTM (2 layers) + fc. 16 blocks x 576 threads (9 waves).
// Waves 0-3 (A): L0 step n.  Waves 4-7 (B): L1 step n-1.  Wave 8 (C): fc step n-2.
// Within A/B: lane cls=l>>4 owns gate cls of elem j=wave*16+(l&15); gather via
// shfl_xor(32) (i<->g, f<->o) then shfl_xor(16) (ig -> f-lane); f-lane owns c.
// ONE __syncthreads per step; h0s/h1s double-buffered fp16 in LDS.
// ---------------------------------------------------------------------------
__global__ __launch_bounds__(576) void k2_pre(
    const float* __restrict__ pg0, const float* __restrict__ preh,
    const float* __restrict__ prec,
    const hf* __restrict__ hWhh0, const hf* __restrict__ hWih1,
    const hf* __restrict__ hWhh1, const hf* __restrict__ hfcW,
    const float* __restrict__ bih1, const float* __restrict__ bhh1,
    const float* __restrict__ fcb, float* __restrict__ xout, int B) {
  const int e = blockIdx.x, tid = threadIdx.x;
  const int wv = tid >> 6, l = tid & 63, cls = l >> 4, sub = l & 15;
  __shared__ __align__(16) hf h0s[2][64];
  __shared__ __align__(16) hf h1s[2][64];

  int wa[32], wb[32];
  float bias = 0.f, c = 0.f;
  const float* pgp = nullptr;
  int j = 0;

  if (wv < 4) {                       // group A: L0
    j = wv * 16 + sub;
    const int r = cls * 64 + j;
    const i4* p0 = (const i4*)(hWhh0 + r * 64);
#pragma unroll
    for (int i = 0; i < 8; ++i) {
      i4 a = p0[i]; wa[4*i]=a.x; wa[4*i+1]=a.y; wa[4*i+2]=a.z; wa[4*i+3]=a.w;
    }
    pgp = pg0 + (size_t)e * 256 + r;
    if (cls == 1) { c = prec[e * 128 + j]; h0s[1][j] = (hf)preh[e * 128 + j]; }
  } else if (wv < 8) {                // group B: L1
    j = (wv - 4) * 16 + sub;
    const int r = cls * 64 + j;
    const i4* p1 = (const i4*)(hWih1 + r * 64);
    const i4* p2 = (const i4*)(hWhh1 + r * 64);
#pragma unroll
    for (int i = 0; i < 8; ++i) {
      i4 a = p1[i]; wa[4*i]=a.x; wa[4*i+1]=a.y; wa[4*i+2]=a.z; wa[4*i+3]=a.w;
      i4 b = p2[i]; wb[4*i]=b.x; wb[4*i+1]=b.y; wb[4*i+2]=b.z; wb[4*i+3]=b.w;
    }
    bias = bih1[r] + bhh1[r];
    if (cls == 1) { c = prec[e * 128 + 64 + j]; h1s[1][j] = (hf)preh[e * 128 + 64 + j]; }
  } else {                            // group C: fc
    j = l;
    const i4* pf = (const i4*)(hfcW + l * 64);
#pragma unroll
    for (int i = 0; i < 8; ++i) {
      i4 a = pf[i]; wa[4*i]=a.x; wa[4*i+1]=a.y; wa[4*i+2]=a.z; wa[4*i+3]=a.w;
    }
    bias = fcb[l];
  }
  __syncthreads();

  float pgA = 0.f, pgB = 0.f;
  if (wv < 4) { pgA = pgp[0]; if (B > 1) pgB = pgp[4096]; }

  for (int n = 0; n < B + 2; ++n) {
    if (wv < 4) {
      if (n < B) {
        const float pgC = (n + 2 < B) ? pgp[(size_t)(n + 2) * 4096] : 0.f;
        const i4* hp = (const i4*)h0s[(n + 1) & 1];      // h0(n-1)
        float a0 = 0.f, a1 = 0.f, a2 = 0.f, a3 = 0.f;
#pragma unroll
        for (int i = 0; i < 8; ++i) {
          i4 h = hp[i];
          a0 = fdot2(wa[4*i],   h.x, a0); a1 = fdot2(wa[4*i+1], h.y, a1);
          a2 = fdot2(wa[4*i+2], h.z, a2); a3 = fdot2(wa[4*i+3], h.w, a3);
        }
        const float pre = (a0 + a1) + (a2 + a3) + pgA;   // pg0 has x-part+biases
        const float act = (cls == 2) ? tanhf_(pre) : sigf(pre);
        const float p32 = __shfl_xor(act, 32);           // cls0<-tanh(g), cls1<-sig(o)
        const float ig = act * p32;                      // cls0: sig(i)*tanh(g)
        const float p16 = __shfl_xor(ig, 16);            // cls1<-ig
        if (cls == 1) {
          c = act * c + p16;                             // act = sig(f)
          const float th = tanhf_(c);
          h0s[n & 1][j] = (hf)(p32 * th);                // p32 = sig(o)
        }
        pgA = pgB; pgB = pgC;
      }
    } else if (wv < 8) {
      if (n >= 1 && n <= B) {
        const i4* hp0 = (const i4*)h0s[(n + 1) & 1];     // h0(n-1)
        const i4* hp1 = (const i4*)h1s[n & 1];           // h1(n-2)
        float a0 = 0.f, a1 = 0.f, a2 = 0.f, a3 = 0.f;
#pragma unroll
        for (int i = 0; i < 8; ++i) {
          i4 h = hp0[i];
          a0 = fdot2(wa[4*i],   h.x, a0); a1 = fdot2(wa[4*i+1], h.y, a1);
          a2 = fdot2(wa[4*i+2], h.z, a2); a3 = fdot2(wa[4*i+3], h.w, a3);
        }
#pragma unroll
        for (int i = 0; i < 8; ++i) {
          i4 h = hp1[i];
          a0 = fdot2(wb[4*i],   h.x, a0); a1 = fdot2(wb[4*i+1], h.y, a1);
          a2 = fdot2(wb[4*i+2], h.z, a2); a3 = fdot2(wb[4*i+3], h.w, a3);
        }
        const float pre = (a0 + a1) + (a2 + a3) + bias;
        const float act = (cls == 2) ? tanhf_(pre) : sigf(pre);
        const float p32 = __shfl_xor(act, 32);
        const float ig = act * p32;
        const float p16 = __shfl_xor(ig, 16);
        if (cls == 1) {
          c = act * c + p16;
          const float th = tanhf_(c);
          h1s[(n + 1) & 1][j] = (hf)(p32 * th);          // h1(n-1) -> buf (n-1)&1
        }
      }
    } else {
      if (n >= 2) {
        const i4* hp1 = (const i4*)h1s[n & 1];           // h1(n-2)
        float a0 = 0.f, a1 = 0.f, a2 = 0.f, a3 = 0.f;
#pragma unroll
        for (int i = 0; i < 8; ++i) {
          i4 h = hp1[i];
          a0 = fdot2(wa[4*i],   h.x, a0); a1 = fdot2(wa[4*i+1], h.y, a1);
          a2 = fdot2(wa[4*i+2], h.z, a2); a3 = fdot2(wa[4*i+3], h.w, a3);
        }
        const float xv = (a0 + a1) + (a2 + a3) + bias;
        xout[((size_t)(n - 2) * E_ + e) * 64 + l] = (xv > 0.f) ? xv : 0.05f * xv;
      }
    }
    __syncthreads();
  }
}

// ---------------------------------------------------------------------------
// K3: communication alpha-LSTM. One wave per timestep t (state resets each t).
// ---------------------------------------------------------------------------
__global__ __launch_bounds__(256) void k3_comm(
    const float* __restrict__ gih0, const float* __restrict__ Whh0,
    const float* __restrict__ Wih1, const float* __restrict__ Whh1,
    const float* __restrict__ bih1, const float* __restrict__ bhh1,
    float* __restrict__ grp, int B) {
  const int w = threadIdx.x >> 6;
  const int l = threadIdx.x & 63;
  const int t = blockIdx.x * 4 + w;

  float wh0a[32], wh0b[32], wi1a[32], wi1b[32], wh1a[32], wh1b[32];
#pragma unroll
  for (int i = 0; i < 32; ++i) {
    wh0a[i] = Whh0[l * 32 + i];         wh0b[i] = Whh0[(l + 64) * 32 + i];
    wi1a[i] = Wih1[l * 32 + i];         wi1b[i] = Wih1[(l + 64) * 32 + i];
    wh1a[i] = Whh1[l * 32 + i];         wh1b[i] = Whh1[(l + 64) * 32 + i];
  }
  const float cb1a = bih1[l] + bhh1[l];
  const float cb1b = bih1[l + 64] + bhh1[l + 64];

  float h0 = 0.0f, c0 = 0.0f, h1 = 0.0f, c1 = 0.0f;
  float al = 1.0f;
  const float* gbase = gih0 + (size_t)t * (E_ * 128);
  for (int r = 0; r < 3; ++r) {
    for (int e = 0; e < E_; ++e) {
      float ga = gbase[e * 128 + l];
      float gb = gbase[e * 128 + l + 64];
#pragma unroll
      for (int k = 0; k < 32; ++k) {
        const float hv = lane_bcast(h0, k);
        ga += wh0a[k] * hv;
        gb += wh0b[k] * hv;
      }
      {
        const float fa = __shfl_xor(ga, 32);
        const float ob = __shfl_xor(gb, 32);
        c0 = sigf(fa) * c0 + al * sigf(ga) * tanhf_(gb);
        h0 = sigf(ob) * tanhf_(c0);
      }
      float ga1 = cb1a, gb1 = cb1b;
#pragma unroll
      for (int k = 0; k < 32; ++k) {
        const float hv = lane_bcast(h0, k);
        ga1 += wi1a[k] * hv;
        gb1 += wi1b[k] * hv;
      }
#pragma unroll
      for (int k = 0; k < 32; ++k) {
        const float hv = lane_bcast(h1, k);
        ga1 += wh1a[k] * hv;
        gb1 += wh1b[k] * hv;
      }
      {
        const float fa = __shfl_xor(ga1, 32);
        const float ob = __shfl_xor(gb1, 32);
        c1 = sigf(fa) * c1 + al * sigf(ga1) * tanhf_(gb1);
        h1 = sigf(ob) * tanhf_(c1);
      }
    }
    al *= 0.333f;
  }
  if (l < 32) {
    grp[(size_t)t * 64 + l] = c0;
    grp[(size_t)t * 64 + 32 + l] = c1;
  }
}

// ---------------------------------------------------------------------------
// K4: per-elevator out-LSTM. 16 blocks x 512 threads (8 waves).
// Elem j = wave*16+(l&15), gate cls=l>>4, row r=cls*128+j; 64 dot2/thread.
// Gate gather via shfl_xor(32)+shfl_xor(16); f-lane owns c; ONE barrier/step.
// Raw depth-2 prefetch of pgo/gg rows (adds deferred to use-site).
// ---------------------------------------------------------------------------
__global__ __launch_bounds__(512) void k4_out(
    const float* __restrict__ pgo, const float* __restrict__ gg,
    const float* __restrict__ outh, const float* __restrict__ outc,
    const hf* __restrict__ hWo, float* __restrict__ noh, int B) {
  const int e = blockIdx.x, tid = threadIdx.x;
  const int wv = tid >> 6, l = tid & 63, cls = l >> 4, sub = l & 15;
  const int j = wv * 16 + sub;
  const int r = cls * 128 + j;
  __shared__ __align__(16) hf hs[2][128];

  int w[64];
  {
    const i4* pw = (const i4*)(hWo + (size_t)r * 128);
#pragma unroll
    for (int i = 0; i < 16; ++i) {
      i4 a = pw[i]; w[4*i]=a.x; w[4*i+1]=a.y; w[4*i+2]=a.z; w[4*i+3]=a.w;
    }
  }
  float c = 0.f;
  if (cls == 1) { c = outc[e * 128 + j]; hs[1][j] = (hf)outh[e * 128 + j]; }
  __syncthreads();

  const float* pgoP = pgo + (size_t)e * 512 + r;   // + tt*8192
  const float* ggP  = gg + r;                      // + tt*512
  float poA = pgoP[0], gA = ggP[0];
  float poB = 0.f, gB = 0.f;
  if (B > 1) { poB = pgoP[8192]; gB = ggP[512]; }

  for (int n = 0; n < B; ++n) {
    float poC = 0.f, gC = 0.f;
    if (n + 2 < B) { poC = pgoP[(size_t)(n + 2) * 8192]; gC = ggP[(size_t)(n + 2) * 512]; }
    const i4* hp = (const i4*)hs[(n + 1) & 1];       // h(n-1)
    float a0 = 0.f, a1 = 0.f, a2 = 0.f, a3 = 0.f;
#pragma unroll
    for (int i = 0; i < 16; ++i) {
      i4 h = hp[i];
      a0 = fdot2(w[4*i],   h.x, a0); a1 = fdot2(w[4*i+1], h.y, a1);
      a2 = fdot2(w[4*i+2], h.z, a2); a3 = fdot2(w[4*i+3], h.w, a3);
    }
    const float pre = (a0 + a1) + (a2 + a3) + poA + gA;  // pgo has biases
    const float act = (cls == 2) ? tanhf_(pre) : sigf(pre);
    const float p32 = __shfl_xor(act, 32);               // cls0<-tanh(g), cls1<-sig(o)
    const float ig = act * p32;
    const float p16 = __shfl_xor(ig, 16);                // cls1<-ig
    if (cls == 1) {
      c = act * c + p16;
      const float th = tanhf_(c);
      const float h = p32 * th;
      hs[n & 1][j] = (hf)h;
      noh[((size_t)n * E_ + e) * 128 + j] = h;
    }
    __syncthreads();
    poA = poB; gA = gB; poB = poC; gB = gC;
  }
}

// ---------------------------------------------------------------------------
// K5: heads. tar = softmax(noh@tarW^T + tb) [64], dir = softmax(noh@dirW^T + db) [3].
// ---------------------------------------------------------------------------
__global__ __launch_bounds__(256) void k5_heads(
    const float* __restrict__ noh, const float* __restrict__ tarW,
    const float* __restrict__ tarb, const float* __restrict__ dirW,
    const float* __restrict__ dirb, float* __restrict__ out) {
  __shared__ float tw[128 * 64];
  __shared__ float tb[64];
  const int tid = threadIdx.x;
  for (int idx = tid; idx < 8192; idx += 256) {
    const int j = idx >> 7, k = idx & 127;
    tw[k * 64 + j] = tarW[idx];
  }
  if (tid < 64) tb[tid] = tarb[tid];
  __syncthreads();
  const int w = tid >> 6, l = tid & 63;
  const float db0 = dirb[0], db1 = dirb[1], db2 = dirb[2];

  for (int p = 0; p < 16; ++p) {
    const int row = blockIdx.x * 64 + p * 4 + w;
    const float na = noh[(size_t)row * 128 + l];
    const float nb = noh[(size_t)row * 128 + 64 + l];
    float acc = tb[l];
#pragma unroll
    for (int k = 0; k < 64; ++k) acc += tw[k * 64 + l] * lane_bcast(na, k);
#pragma unroll
    for (int k = 0; k < 64; ++k) acc += tw[(64 + k) * 64 + l] * lane_bcast(nb, k);
    float m = acc;
#pragma unroll
    for (int s = 32; s; s >>= 1) m = fmaxf(m, __shfl_xor(m, s));
    const float ex = __expf(acc - m);
    float sm = ex;
#pragma unroll
    for (int s = 32; s; s >>= 1) sm += __shfl_xor(sm, s);
    out[(size_t)row * 67 + l] = ex / sm;
    float d0 = dirW[l] * na + dirW[64 + l] * nb;
    float d1 = dirW[128 + l] * na + dirW[192 + l] * nb;
    float d2 = dirW[256 + l] * na + dirW[320 + l] * nb;
#pragma unroll
    for (int s = 32; s; s >>= 1) {
      d0 += __shfl_xor(d0, s);
      d1 += __shfl_xor(d1, s);
      d2 += __shfl_xor(d2, s);
    }
    d0 += db0; d1 += db1; d2 += db2;
    const float dm = fmaxf(d0, fmaxf(d1, d2));
    const float e0 = __expf(d0 - dm), e1 = __expf(d1 - dm), e2 = __expf(d2 - dm);
    const float ds = e0 + e1 + e2;
    if (l < 3) out[(size_t)row * 67 + 64 + l] = (l == 0 ? e0 : (l == 1 ? e1 : e2)) / ds;
  }
}

// ---------------------------------------------------------------------------
extern "C" void kernel_launch(void* const* d_in, const int* in_sizes, int n_in,
                              void* d_out, int out_size, void* d_ws, size_t ws_size,
                              hipStream_t stream) {
  const float* features = (const float*)d_in[0];
  const float* pre_h    = (const float*)d_in[1];
  const float* pre_c    = (const float*)d_in[2];
  const float* out_h    = (const float*)d_in[3];
  const float* out_c    = (const float*)d_in[4];
  const float* pre_Wih0 = (const float*)d_in[5];
  const float* pre_Whh0 = (const float*)d_in[6];
  const float* pre_bih0 = (const float*)d_in[7];
  const float* pre_bhh0 = (const float*)d_in[8];
  const float* pre_Wih1 = (const float*)d_in[9];
  const float* pre_Whh1 = (const float*)d_in[10];
  const float* pre_bih1 = (const float*)d_in[11];
  const float* pre_bhh1 = (const float*)d_in[12];
  const float* fc_W     = (const float*)d_in[13];
  const float* fc_b     = (const float*)d_in[14];
  const float* comm_Wih0 = (const float*)d_in[15];
  const float* comm_Whh0 = (const float*)d_in[16];
  const float* comm_bih0 = (const float*)d_in[17];
  const float* comm_bhh0 = (const float*)d_in[18];
  const float* comm_Wih1 = (const float*)d_in[19];
  const float* comm_Whh1 = (const float*)d_in[20];
  const float* comm_bih1 = (const float*)d_in[21];
  const float* comm_bhh1 = (const float*)d_in[22];
  const float* out_Wih  = (const float*)d_in[23];
  const float* out_Whh  = (const float*)d_in[24];
  const float* out_bih  = (const float*)d_in[25];
  const float* out_bhh  = (const float*)d_in[26];
  const float* tar_W    = (const float*)d_in[27];
  const float* tar_b    = (const float*)d_in[28];
  const float* dir_W    = (const float*)d_in[29];
  const float* dir_b    = (const float*)d_in[30];

  const int B = in_sizes[0] / (E_ * F_);   // 2048
  float* ws = (float*)d_ws;
  float* pg0 = ws;                                  // [B*16, 256]
  float* pgo = pg0 + (size_t)B * E_ * 256;          // [B*16, 512]
  float* xbf = pgo + (size_t)B * E_ * 512;          // [B*16, 64]
  float* gih = xbf + (size_t)B * E_ * 64;           // [B*16, 128]
  float* grp = gih + (size_t)B * E_ * 128;          // [B, 64]
  float* gg  = grp + (size_t)B * 64;                // [B, 512]
  float* noh = gg + (size_t)B * 512;                // [B*16, 128]
  hf* hWhh0 = (hf*)(noh + (size_t)B * E_ * 128);    // [256*64]
  hf* hWih1 = hWhh0 + 256 * 64;                     // [256*64]
  hf* hWhh1 = hWih1 + 256 * 64;                     // [256*64]
  hf* hfcW  = hWhh1 + 256 * 64;                     // [64*64]
  hf* hWo   = hfcW + 64 * 64;                       // [512*128]
  (void)ws_size; (void)n_in; (void)out_size;

  // W0: fp32 -> fp16 weight packs for the recurrence kernels
  f2h_kernel<<<(256 * 64 + 255) / 256, 256, 0, stream>>>(pre_Whh0, hWhh0, 256 * 64);
  f2h_kernel<<<(256 * 64 + 255) / 256, 256, 0, stream>>>(pre_Wih1, hWih1, 256 * 64);
  f2h_kernel<<<(256 * 64 + 255) / 256, 256, 0, stream>>>(pre_Whh1, hWhh1, 256 * 64);
  f2h_kernel<<<(64 * 64 + 255) / 256, 256, 0, stream>>>(fc_W, hfcW, 64 * 64);
  f2h_kernel<<<(512 * 128 + 255) / 256, 256, 0, stream>>>(out_Whh, hWo, 512 * 128);

  const int MB = B * E_ / 64;

  // G1: pre-LSTM layer0 input projection (+ both biases)
  gemm_k<<<dim3(MB, 2), 256, 0, stream>>>(features, 128, pre_Wih0, 128, 0,
                                          pre_bih0, pre_bhh0, pg0, 256, 128);
  // G2: out-LSTM feat-half input projection (+ both biases)
  gemm_k<<<dim3(MB, 4), 256, 0, stream>>>(features, 128, out_Wih, 192, 64,
                                          out_bih, out_bhh, pgo, 512, 128);
  // K2: pre recurrence (writes x)
  k2_pre<<<E_, 576, 0, stream>>>(pg0, pre_h, pre_c, hWhh0, hWih1, hWhh1, hfcW,
                                 pre_bih1, pre_bhh1, fc_b, xbf, B);
  // G4: comm layer0 input projection (+ both biases)
  gemm_k<<<dim3(MB, 1), 256, 0, stream>>>(xbf, 64, comm_Wih0, 64, 0,
                                          comm_bih0, comm_bhh0, gih, 128, 64);
  // K3: comm chains (writes group cell states)
  k3_comm<<<B / 4, 256, 0, stream>>>(gih, comm_Whh0, comm_Wih1, comm_Whh1,
                                     comm_bih1, comm_bhh1, grp, B);
  // G6: out-LSTM group-half input projection
  gemm_k<<<dim3(B / 64, 4), 256, 0, stream>>>(grp, 64, out_Wih, 192, 0,
                                              nullptr, nullptr, gg, 512, 64);
  // K4: out recurrence (writes noh)
  k4_out<<<E_, 512, 0, stream>>>(pgo, gg, out_h, out_c, hWo, noh, B);
  // K5: heads + softmax -> d_out [B,16,67]
  k5_heads<<<B * E_ / 64, 256, 0, stream>>>(noh, tar_W, tar_b, dir_W, dir_b,
                                            (float*)d_out);
}